// Round 17
// baseline (377.444 us; speedup 1.0000x reference)
//
#include <hip/hip_runtime.h>

#define S_LEN 1024
#define HID 3584
#define NH 28
#define NKV 4
#define DH 128
#define GQ 7
#define SCALE 0.08838834764831845f
#define LOG2E 1.44269504088896f
#define CEXP (SCALE * LOG2E)
#define KDIM 3584
#define NT (KDIM / 64)

typedef float f32x4 __attribute__((ext_vector_type(4)));
typedef __bf16 bf16x8 __attribute__((ext_vector_type(8)));
typedef __bf16 bf16x4 __attribute__((ext_vector_type(4)));

#define BAR() __builtin_amdgcn_s_barrier()
#define VMCNT(n) asm volatile("s_waitcnt vmcnt(" #n ")" ::: "memory")

__device__ __forceinline__ void gl_lds16(const void* g, void* l) {
  __builtin_amdgcn_global_load_lds((const __attribute__((address_space(1))) unsigned int*)g,
                                   (__attribute__((address_space(3))) unsigned int*)l, 16, 0, 0);
}

__device__ __forceinline__ __bf16 f2bf(float f) { return (__bf16)f; }
__device__ __forceinline__ float bf2f(__bf16 h) { return (float)h; }

// ---------------- fused f32 -> bf16 convert: hs, Wq, Wk, Wv (+bias concat) ----------------
__global__ __launch_bounds__(256) void cvt_all(const float* __restrict__ hs,
                                               const float* __restrict__ Wq,
                                               const float* __restrict__ Wk,
                                               const float* __restrict__ Wv,
                                               const float* __restrict__ bq,
                                               const float* __restrict__ bk,
                                               const float* __restrict__ bv,
                                               __bf16* __restrict__ Xb,
                                               __bf16* __restrict__ Wqkv,
                                               float* __restrict__ biasq) {
  if (blockIdx.x == 11648) {
    int t = threadIdx.x;
#pragma unroll
    for (int j = 0; j < 18; ++j) {
      int i = t * 18 + j;
      biasq[i] = (i < 3584) ? bq[i] : (i < 4096 ? bk[i - 3584] : bv[i - 4096]);
    }
    return;
  }
  int i = blockIdx.x * blockDim.x + threadIdx.x;  // 8-elem units, total 2981888
  const float* src;
  __bf16* dst;
  int j;
  if (i < 917504) { src = hs; dst = Xb; j = i; }
  else if (i < 2523136) { src = Wq; dst = Wqkv; j = i - 917504; }
  else if (i < 2752512) { src = Wk; dst = Wqkv + 12845056; j = i - 2523136; }
  else { src = Wv; dst = Wqkv + 14680064; j = i - 2752512; }
  f32x4 a = ((const f32x4*)src)[2 * j], b2 = ((const f32x4*)src)[2 * j + 1];
  bf16x8 o;
  o[0] = f2bf(a[0]); o[1] = f2bf(a[1]); o[2] = f2bf(a[2]); o[3] = f2bf(a[3]);
  o[4] = f2bf(b2[0]); o[5] = f2bf(b2[1]); o[6] = f2bf(b2[2]); o[7] = f2bf(b2[3]);
  ((bf16x8*)dst)[j] = o;
}

// ============== 2-phase GEMM, 256x192 tile, QKV epilogue + Wo-cvt filler ==============
// V is written DIRECTLY in VT (B,KV,D,S) layout (R15-verified).
__global__ __launch_bounds__(512, 2) void gemm192qkv(const __bf16* __restrict__ A,
                                                     const __bf16* __restrict__ Bw,
                                                     const float* __restrict__ bias,
                                                     __bf16* __restrict__ qb,
                                                     __bf16* __restrict__ kb,
                                                     __bf16* __restrict__ vt,
                                                     const float* __restrict__ Wo,
                                                     __bf16* __restrict__ Wob) {
  const int t_ = threadIdx.x;
  const int xcd = blockIdx.x & 7, slot = blockIdx.x >> 3;
  if (slot >= 24) {
    int cvtid = xcd * 8 + (slot - 24);  // 0..63
#pragma unroll
    for (int j = 0; j < 49; ++j) {
      int u = cvtid * 25088 + j * 512 + t_;
      f32x4 a = ((const f32x4*)Wo)[2 * u], b2 = ((const f32x4*)Wo)[2 * u + 1];
      bf16x8 o;
      o[0] = f2bf(a[0]); o[1] = f2bf(a[1]); o[2] = f2bf(a[2]); o[3] = f2bf(a[3]);
      o[4] = f2bf(b2[0]); o[5] = f2bf(b2[1]); o[6] = f2bf(b2[2]); o[7] = f2bf(b2[3]);
      ((bf16x8*)Wob)[u] = o;
    }
    return;
  }

  __shared__ __bf16 Asb[2][256 * 64];
  __shared__ __bf16 Bsb[2][192 * 64];
  int wg = xcd * 24 + slot;
  const long bm = (long)(wg / 24) * 256, bn = (long)(wg % 24) * 192;

  const int lane = t_ & 63, w = t_ >> 6;
  const int wm = w >> 2, wn = w & 3;
  const int l15 = lane & 15, g = lane >> 4;
  const int sw = l15 & 7;
  const int aRow0 = wm * 128 + l15, bRow0 = wn * 48 + l15;

  const int srow = t_ >> 3;
  const int cOff = ((t_ & 7) ^ (srow & 7)) << 3;
  const __bf16* Agp = A + (bm + srow) * (long)KDIM + cOff;
  const __bf16* Bgp = Bw + (bn + srow) * (long)KDIM + cOff;

  auto stageA = [&](int i, int k0, int c) {
    gl_lds16(Agp + (long)i * 64 * KDIM + k0, &Asb[c][(i * 512 + t_) * 8]);
  };
  auto stageB = [&](int i, int k0, int c) {
    gl_lds16(Bgp + (long)i * 64 * KDIM + k0, &Bsb[c][(i * 512 + t_) * 8]);
  };
  auto lda = [&](int c, int fm, int kh) -> bf16x8 {
    return *(const bf16x8*)(&Asb[c][(aRow0 + fm * 16) * 64 + (((kh * 4 + g) ^ sw) << 3)]);
  };
  auto ldb = [&](int c, int fn, int kh) -> bf16x8 {
    return *(const bf16x8*)(&Bsb[c][(bRow0 + fn * 16) * 64 + (((kh * 4 + g) ^ sw) << 3)]);
  };

  f32x4 acc[8][3] = {};
  bf16x8 a[4][2], b[3][2];

#pragma unroll
  for (int i = 0; i < 4; ++i) stageA(i, 0, 0);
#pragma unroll
  for (int i = 0; i < 3; ++i) stageB(i, 0, 0);
#pragma unroll
  for (int i = 0; i < 4; ++i) stageA(i, 64, 1);
#pragma unroll
  for (int i = 0; i < 3; ++i) stageB(i, 64, 1);
  VMCNT(7);
  BAR();

#pragma unroll 2
  for (int t = 0; t < NT; ++t) {
    const int c = t & 1;
    const int k2 = (t + 2) << 6;
    const bool n2 = (t + 2) < NT;
    // ---- P0: fm0-3 x fn0-2 ----
#pragma unroll
    for (int fm = 0; fm < 4; ++fm) { a[fm][0] = lda(c, fm, 0); a[fm][1] = lda(c, fm, 1); }
#pragma unroll
    for (int fn = 0; fn < 3; ++fn) { b[fn][0] = ldb(c, fn, 0); b[fn][1] = ldb(c, fn, 1); }
    if (t >= 1 && (t + 1) < NT) { stageA(1, (t + 1) << 6, c ^ 1); stageA(3, (t + 1) << 6, c ^ 1); }
    BAR();
    __builtin_amdgcn_s_setprio(1);
#pragma unroll
    for (int fm = 0; fm < 4; ++fm)
#pragma unroll
      for (int fn = 0; fn < 3; ++fn) {
        acc[fm][fn] = __builtin_amdgcn_mfma_f32_16x16x32_bf16(a[fm][0], b[fn][0], acc[fm][fn], 0, 0, 0);
        acc[fm][fn] = __builtin_amdgcn_mfma_f32_16x16x32_bf16(a[fm][1], b[fn][1], acc[fm][fn], 0, 0, 0);
      }
    __builtin_amdgcn_s_setprio(0);
    BAR();
    // ---- P1: fm4-7 x fn0-2 ----
#pragma unroll
    for (int fm = 0; fm < 4; ++fm) { a[fm][0] = lda(c, 4 + fm, 0); a[fm][1] = lda(c, 4 + fm, 1); }
    if (n2) { stageA(0, k2, c); stageA(2, k2, c); stageB(0, k2, c); stageB(1, k2, c); stageB(2, k2, c); }
    BAR();
    __builtin_amdgcn_s_setprio(1);
#pragma unroll
    for (int fm = 0; fm < 4; ++fm)
#pragma unroll
      for (int fn = 0; fn < 3; ++fn) {
        acc[4 + fm][fn] = __builtin_amdgcn_mfma_f32_16x16x32_bf16(a[fm][0], b[fn][0], acc[4 + fm][fn], 0, 0, 0);
        acc[4 + fm][fn] = __builtin_amdgcn_mfma_f32_16x16x32_bf16(a[fm][1], b[fn][1], acc[4 + fm][fn], 0, 0, 0);
      }
    __builtin_amdgcn_s_setprio(0);
    if (t < NT - 1) {
      if (n2) { VMCNT(5); } else { VMCNT(0); }
    }
    BAR();
  }

  // epilogue: QKV scatter (+bias); V goes directly to VT layout
#pragma unroll
  for (int fm = 0; fm < 8; ++fm) {
#pragma unroll
    for (int fn = 0; fn < 3; ++fn) {
      int col = (int)bn + wn * 48 + fn * 16 + l15;
      float bval = bias[col];
      int row0 = (int)bm + wm * 128 + fm * 16 + g * 4;
      int b_ = row0 >> 10, s0 = row0 & 1023;
      if (col < 3584) {
        int h_ = col >> 7, d_ = col & 127;
#pragma unroll
        for (int i = 0; i < 4; ++i)
          qb[((((long)b_ * NH + h_) << 10) + s0 + i) * DH + d_] = f2bf(acc[fm][fn][i] + bval);
      } else if (col < 4096) {
        int c2 = col - 3584, h_ = c2 >> 7, d_ = c2 & 127;
#pragma unroll
        for (int i = 0; i < 4; ++i)
          kb[((((long)b_ * NKV + h_) << 10) + s0 + i) * DH + d_] = f2bf(acc[fm][fn][i] + bval);
      } else {
        int c2 = col - 4096, h_ = c2 >> 7, d_ = c2 & 127;
        bf16x4 pv;
#pragma unroll
        for (int i = 0; i < 4; ++i) pv[i] = f2bf(acc[fm][fn][i] + bval);
        *(bf16x4*)(vt + ((((long)b_ * NKV + h_) * DH + d_) << 10) + s0) = pv;
      }
    }
  }
}

// ============== 2-phase GEMM, 256x128 tile, f32-out epilogue (out-proj) ==============
__global__ __launch_bounds__(512, 2) void gemm128out(const __bf16* __restrict__ A,
                                                     const __bf16* __restrict__ Bw,
                                                     float* __restrict__ outf) {
  __shared__ __bf16 Asb[2][256 * 64];
  __shared__ __bf16 Bsb[2][128 * 64];
  const int t_ = threadIdx.x;
  const int nwg = 224, NBN = 28;
  int wg = (blockIdx.x & 7) * (nwg >> 3) + (blockIdx.x >> 3);
  const long bm = (long)(wg / NBN) * 256, bn = (long)(wg % NBN) * 128;

  const int lane = t_ & 63, w = t_ >> 6;
  const int wm = w >> 2, wn = w & 3;
  const int l15 = lane & 15, g = lane >> 4;
  const int sw = l15 & 7;
  const int aRow0 = wm * 128 + l15, bRow0 = wn * 32 + l15;

  const int srow = t_ >> 3;
  const int cOff = ((t_ & 7) ^ (srow & 7)) << 3;
  const __bf16* Agp = A + (bm + srow) * (long)KDIM + cOff;
  const __bf16* Bgp = Bw + (bn + srow) * (long)KDIM + cOff;

  auto stageA = [&](int i, int k0, int c) {
    gl_lds16(Agp + (long)i * 64 * KDIM + k0, &Asb[c][(i * 512 + t_) * 8]);
  };
  auto stageB = [&](int i, int k0, int c) {
    gl_lds16(Bgp + (long)i * 64 * KDIM + k0, &Bsb[c][(i * 512 + t_) * 8]);
  };
  auto lda = [&](int c, int fm, int kh) -> bf16x8 {
    return *(const bf16x8*)(&Asb[c][(aRow0 + fm * 16) * 64 + (((kh * 4 + g) ^ sw) << 3)]);
  };
  auto ldb = [&](int c, int fn, int kh) -> bf16x8 {
    return *(const bf16x8*)(&Bsb[c][(bRow0 + fn * 16) * 64 + (((kh * 4 + g) ^ sw) << 3)]);
  };

  f32x4 acc[8][2] = {};
  bf16x8 a[4][2], b[2][2];

#pragma unroll
  for (int i = 0; i < 4; ++i) stageA(i, 0, 0);
  stageB(0, 0, 0); stageB(1, 0, 0);
#pragma unroll
  for (int i = 0; i < 4; ++i) stageA(i, 64, 1);
  stageB(0, 64, 1); stageB(1, 64, 1);
  VMCNT(6);
  BAR();

#pragma unroll 2
  for (int t = 0; t < NT; ++t) {
    const int c = t & 1;
    const int k2 = (t + 2) << 6;
    const bool n2 = (t + 2) < NT;
#pragma unroll
    for (int fm = 0; fm < 4; ++fm) { a[fm][0] = lda(c, fm, 0); a[fm][1] = lda(c, fm, 1); }
#pragma unroll
    for (int fn = 0; fn < 2; ++fn) { b[fn][0] = ldb(c, fn, 0); b[fn][1] = ldb(c, fn, 1); }
    if (t >= 1 && (t + 1) < NT) { stageA(1, (t + 1) << 6, c ^ 1); stageA(3, (t + 1) << 6, c ^ 1); }
    BAR();
    __builtin_amdgcn_s_setprio(1);
#pragma unroll
    for (int fm = 0; fm < 4; ++fm)
#pragma unroll
      for (int fn = 0; fn < 2; ++fn) {
        acc[fm][fn] = __builtin_amdgcn_mfma_f32_16x16x32_bf16(a[fm][0], b[fn][0], acc[fm][fn], 0, 0, 0);
        acc[fm][fn] = __builtin_amdgcn_mfma_f32_16x16x32_bf16(a[fm][1], b[fn][1], acc[fm][fn], 0, 0, 0);
      }
    __builtin_amdgcn_s_setprio(0);
    BAR();
#pragma unroll
    for (int fm = 0; fm < 4; ++fm) { a[fm][0] = lda(c, 4 + fm, 0); a[fm][1] = lda(c, 4 + fm, 1); }
    if (n2) { stageA(0, k2, c); stageA(2, k2, c); stageB(0, k2, c); stageB(1, k2, c); }
    BAR();
    __builtin_amdgcn_s_setprio(1);
#pragma unroll
    for (int fm = 0; fm < 4; ++fm)
#pragma unroll
      for (int fn = 0; fn < 2; ++fn) {
        acc[4 + fm][fn] = __builtin_amdgcn_mfma_f32_16x16x32_bf16(a[fm][0], b[fn][0], acc[4 + fm][fn], 0, 0, 0);
        acc[4 + fm][fn] = __builtin_amdgcn_mfma_f32_16x16x32_bf16(a[fm][1], b[fn][1], acc[4 + fm][fn], 0, 0, 0);
      }
    __builtin_amdgcn_s_setprio(0);
    if (t < NT - 1) {
      if (n2) { VMCNT(4); } else { VMCNT(0); }
    }
    BAR();
  }

#pragma unroll
  for (int fm = 0; fm < 8; ++fm) {
#pragma unroll
    for (int fn = 0; fn < 2; ++fn) {
      int col = (int)bn + wn * 32 + fn * 16 + l15;
#pragma unroll
      for (int i = 0; i < 4; ++i) {
        int row = (int)bm + wm * 128 + fm * 16 + g * 4 + i;
        outf[(long)row * HID + col] = acc[fm][fn][i];
      }
    }
  }
}

// ---------------- K-RoPE (in-place; V handled in QKV epilogue, Q in attn) ----------------
__global__ __launch_bounds__(256) void k_rope(__bf16* __restrict__ Kb,
                                              const float* __restrict__ cosb,
                                              const float* __restrict__ sinb) {
  int gid = blockIdx.x * blockDim.x + threadIdx.x;  // 524288
  int d = gid & 63;
  int r = gid >> 6;  // 0..8191
  __bf16* ptr = Kb + (long)r * DH;
  int s = r & 1023, b = r >> 12;
  const float* cb = cosb + ((long)(b << 10) + s) * DH;
  const float* sb = sinb + ((long)(b << 10) + s) * DH;
  float x1 = bf2f(ptr[d]), x2 = bf2f(ptr[d + 64]);
  ptr[d] = f2bf(x1 * cb[d] - x2 * sb[d]);
  ptr[d + 64] = f2bf(x2 * cb[d + 64] + x1 * sb[d + 64]);
}

// ---------------- fused attention: SINGLE pass, E kept in registers ----------------
// R16 + fix: O's il must be indexed by the PV OUTPUT row (g*4+i), not this lane's
// softmax row (l15) — redistributed via per-wave Ilds (R4-verified pattern).
__global__ __launch_bounds__(256, 2) void attn_fused(const __bf16* __restrict__ Qb,
                                                     const __bf16* __restrict__ Kb,
                                                     const __bf16* __restrict__ VTb,
                                                     const float* __restrict__ cosb,
                                                     const float* __restrict__ sinb,
                                                     float* __restrict__ Pout,
                                                     __bf16* __restrict__ Ob) {
  const int bid = blockIdx.x;
  const int t = threadIdx.x;
  if (bid >= 448) {
    const int zid = bid - 448;
    f32x4 z = {0.f, 0.f, 0.f, 0.f};
    for (int cc = zid; cc < 840; cc += 64) {
      int hh = cc / 15, rt = cc % 15;
      int row = (rt << 6) + (t >> 2);
      float* rowp = Pout + ((long)hh << 20) + ((long)row << 10);
      int c0 = (rt + 1) << 6;
      int ncol4 = (1024 - c0) >> 2;
      for (int c4 = (t & 3); c4 < ncol4; c4 += 4)
        __builtin_nontemporal_store(z, (f32x4*)(rowp + c0 + c4 * 4));
    }
    return;
  }
  const int pair = bid & 7;
  const int rest = bid >> 3;  // 0..55
  const int h = rest % 28;
  const int b = rest / 28;
  const int kv = h / GQ;
  const int lane = t & 63, w = t >> 6;
  const int l15 = lane & 15, g = (lane >> 4) & 3;
  const int lk = g * 8;
  const int swz = (l15 & 7) << 3;

  __shared__ __bf16 Kt[2][64 * 128];
  __shared__ __bf16 Vt[2][128 * 64];
  __shared__ __bf16 Pl[4][16 * 68];
  __shared__ float Ilds[4][16];

  const __bf16* Kg = Kb + (long)(b * NKV + kv) * S_LEN * DH;
  const __bf16* Vg = VTb + (long)(b * NKV + kv) * DH * S_LEN;
  float* Pb0 = Pout + (long)(b * NH + h) * S_LEN * S_LEN;

  auto stageK = [&](int kt, int c) {
#pragma unroll
    for (int is = 0; is < 4; ++is) {
      int chunk = is * 256 + t;
      int row = chunk >> 4, slot = chunk & 15;
      gl_lds16(Kg + (long)(kt * 64 + row) * DH + ((slot ^ (row & 7)) * 8), &Kt[c][chunk * 8]);
    }
  };
  auto stageV = [&](int kt, int c) {
#pragma unroll
    for (int is = 0; is < 4; ++is) {
      int chunk = is * 256 + t;
      int row = chunk >> 3, slot = chunk & 7;
      gl_lds16(Vg + (long)row * S_LEN + kt * 64 + ((slot ^ (row & 7)) * 8), &Vt[c][chunk * 8]);
    }
  };

  for (int halfq = 0; halfq < 2; ++halfq) {
    const int bx = halfq ? (15 - pair) : pair;
    const int q0 = bx * 64;
    const int row_q = q0 + w * 16 + l15;

    // ---- stage RAW Q (64x128, swizzled) into Kt[0]; RoPE applied in registers ----
    const __bf16* Qg = Qb + (((long)(b * NH + h) << 10) + q0) * DH;
#pragma unroll
    for (int is = 0; is < 4; ++is) {
      int chunk = is * 256 + t;
      int row = chunk >> 4, slot = chunk & 15;
      gl_lds16(Qg + (long)row * DH + ((slot ^ (row & 7)) * 8), &Kt[0][chunk * 8]);
    }
    __syncthreads();
    bf16x8 qraw[4];
#pragma unroll
    for (int kk = 0; kk < 4; ++kk)
      qraw[kk] = *(const bf16x8*)(&Kt[0][(w * 16 + l15) * 128 + ((kk * 32 + lk) ^ swz)]);
    __syncthreads();

    // issue tile-0 stages early; their latency hides under the RoPE VALU below
    stageK(0, 0);
    stageV(0, 0);

    // in-register RoPE (fragment read cancels staging swizzle -> true column kk*32+lk+j)
    const float* cb = cosb + (((long)(b << 10) + row_q) << 7);
    const float* sb = sinb + (((long)(b << 10) + row_q) << 7);
    bf16x8 aq[4];
#pragma unroll
    for (int kk = 0; kk < 2; ++kk) {
      int dbase = kk * 32 + lk;  // true column in [0,64), 8-aligned
      f32x4 c0 = *(const f32x4*)(cb + dbase), c1 = *(const f32x4*)(cb + dbase + 4);
      f32x4 s0 = *(const f32x4*)(sb + dbase), s1 = *(const f32x4*)(sb + dbase + 4);
      f32x4 c2 = *(const f32x4*)(cb + dbase + 64), c3 = *(const f32x4*)(cb + dbase + 68);
      f32x4 s2 = *(const f32x4*)(sb + dbase + 64), s3 = *(const f32x4*)(sb + dbase + 68);
#pragma unroll
      for (int j = 0; j < 4; ++j) {
        float lo0 = bf2f(qraw[kk][j]), hi0 = bf2f(qraw[kk + 2][j]);
        float lo1 = bf2f(qraw[kk][4 + j]), hi1 = bf2f(qraw[kk + 2][4 + j]);
        aq[kk][j] = f2bf(lo0 * c0[j] - hi0 * s0[j]);
        aq[kk][4 + j] = f2bf(lo1 * c1[j] - hi1 * s1[j]);
        aq[kk + 2][j] = f2bf(hi0 * c2[j] + lo0 * s2[j]);
        aq[kk + 2][4 + j] = f2bf(hi1 * c3[j] + lo1 * s3[j]);
      }
    }

    // ---------- single pass: QK -> E -> (regs) -> PV(unnormalized) ----------
    float lsum = 0.f;
    f32x4 oa[8] = {};
    bf16x8 eA[16], eB[16];
#pragma unroll
    for (int kt = 0; kt < 16; ++kt) {
      if (kt <= bx) {  // block-uniform guard (full unroll keeps eA/eB indices static)
        const int c = kt & 1;
        if (kt < bx) { stageK(kt + 1, c ^ 1); stageV(kt + 1, c ^ 1); VMCNT(8); } else { VMCNT(0); }
        BAR();
#pragma unroll
        for (int fn = 0; fn < 4; ++fn) {
          f32x4 acc = {};
#pragma unroll
          for (int kk = 0; kk < 4; ++kk) {
            bf16x8 kf = *(const bf16x8*)(&Kt[c][(fn * 16 + l15) * 128 + ((kk * 32 + lk) ^ swz)]);
            acc = __builtin_amdgcn_mfma_f32_16x16x32_bf16(kf, aq[kk], acc, 0, 0, 0);
          }
          int colbase = kt * 64 + fn * 16 + g * 4;
          bf16x4 pb;
#pragma unroll
          for (int i = 0; i < 4; ++i) {
            float e = (colbase + i <= row_q) ? exp2f(acc[i] * CEXP) : 0.f;
            lsum += e;
            pb[i] = f2bf(e);
          }
          *(bf16x4*)(&Pl[w][l15 * 68 + fn * 16 + g * 4]) = pb;
        }
        bf16x8 ap0 = *(const bf16x8*)(&Pl[w][l15 * 68 + lk]);
        bf16x8 ap1 = *(const bf16x8*)(&Pl[w][l15 * 68 + 32 + lk]);
        eA[kt] = ap0;
        eB[kt] = ap1;
#pragma unroll
        for (int dn = 0; dn < 8; ++dn) {
          bf16x8 bv0 = *(const bf16x8*)(&Vt[c][(dn * 16 + l15) * 64 + (lk ^ swz)]);
          bf16x8 bv1 = *(const bf16x8*)(&Vt[c][(dn * 16 + l15) * 64 + ((32 + lk) ^ swz)]);
          oa[dn] = __builtin_amdgcn_mfma_f32_16x16x32_bf16(ap0, bv0, oa[dn], 0, 0, 0);
          oa[dn] = __builtin_amdgcn_mfma_f32_16x16x32_bf16(ap1, bv1, oa[dn], 0, 0, 0);
        }
        BAR();
      }
    }
    lsum += __shfl_xor(lsum, 16);
    lsum += __shfl_xor(lsum, 32);
    const float il = 1.f / lsum;
    if (lane < 16) Ilds[w][l15] = il;  // per-row il for the O rescale (cross-lane)

    // ---------- store-only P epilogue: P = E * il (nontemporal; own row) ----------
#pragma unroll
    for (int kt = 0; kt < 16; ++kt) {
      if (kt <= bx) {
        float* pb = Pb0 + ((long)row_q << 10) + kt * 64;
        f32x4 p0, p1, p2, p3;
#pragma unroll
        for (int j = 0; j < 4; ++j) {
          p0[j] = bf2f(eA[kt][j]) * il;
          p1[j] = bf2f(eA[kt][4 + j]) * il;
          p2[j] = bf2f(eB[kt][j]) * il;
          p3[j] = bf2f(eB[kt][4 + j]) * il;
        }
        __builtin_nontemporal_store(p0, (f32x4*)(pb + lk));
        __builtin_nontemporal_store(p1, (f32x4*)(pb + lk + 4));
        __builtin_nontemporal_store(p2, (f32x4*)(pb + 32 + lk));
        __builtin_nontemporal_store(p3, (f32x4*)(pb + 32 + lk + 4));
      }
    }

    // write O (bf16, (B,S,H*D)); PV output row = g*4+i -> use that row's il
#pragma unroll
    for (int dn = 0; dn < 8; ++dn) {
#pragma unroll
      for (int i = 0; i < 4; ++i) {
        int row = q0 + w * 16 + g * 4 + i;
        float sc = Ilds[w][g * 4 + i];
        Ob[(long)(b * S_LEN + row) * HID + h * DH + dn * 16 + l15] = f2bf(oa[dn][i] * sc);
      }
    }
  }
}

extern "C" void kernel_launch(void* const* d_in, const int* in_sizes, int n_in,
                              void* d_out, int out_size, void* d_ws, size_t ws_size,
                              hipStream_t stream) {
  const float* hs = (const float*)d_in[0];
  const float* cosb = (const float*)d_in[1];
  const float* sinb = (const float*)d_in[2];
  const float* Wq = (const float*)d_in[4];
  const float* bq = (const float*)d_in[5];
  const float* Wk = (const float*)d_in[6];
  const float* bk = (const float*)d_in[7];
  const float* Wv = (const float*)d_in[8];
  const float* bv = (const float*)d_in[9];
  const float* Wo = (const float*)d_in[10];

  float* out = (float*)d_out;
  float* attn_out = out;             // 2*1024*3584
  float* attn_w = out + 7340032;     // 2*28*1024*1024

  char* ws = (char*)d_ws;
  size_t off = 0;
  auto alloc = [&](size_t bytes) {
    void* p = ws + off;
    off += (bytes + 255) & ~(size_t)255;
    return p;
  };
  __bf16* Xb = (__bf16*)alloc(2048LL * 3584 * 2);
  __bf16* Wqkv = (__bf16*)alloc(4608LL * 3584 * 2);
  __bf16* Wob = (__bf16*)alloc(3584LL * 3584 * 2);
  float* biasq = (float*)alloc(4608 * 4);
  __bf16* Qb = (__bf16*)alloc(2LL * 28 * 1024 * 128 * 2);
  __bf16* Kb = (__bf16*)alloc(2LL * 4 * 1024 * 128 * 2);
  __bf16* VT = (__bf16*)alloc(2LL * 4 * 1024 * 128 * 2);
  __bf16* Ob = (__bf16*)alloc(2048LL * 3584 * 2);

  // converts hs, Wq, Wk, Wv (+bias); Wo handled by gemm192qkv's filler blocks
  cvt_all<<<11649, 256, 0, stream>>>(hs, Wq, Wk, Wv, bq, bk, bv, Xb, Wqkv, biasq);

  // slot<24 (24/XCD): QKV GEMM (192 blocks); slot>=24: Wo cvt (64 blocks).
  // V is written directly in VT layout by the epilogue.
  gemm192qkv<<<256, 512, 0, stream>>>(Xb, Wqkv, biasq, Qb, Kb, VT, Wo, Wob);

  // K-RoPE only (Q-RoPE in attn, V-transpose in QKV epilogue)
  k_rope<<<2048, 256, 0, stream>>>(Kb, cosb, sinb);

  // 448 compute blocks + 64 zero-fill filler blocks (all co-resident at 2/CU)
  attn_fused<<<512, 256, 0, stream>>>(Qb, Kb, VT, cosb, sinb, attn_w, Ob);

  gemm128out<<<224, 512, 0, stream>>>(Ob, Wob, attn_out);
}

// Round 18
// 247.287 us; speedup vs baseline: 1.5263x; 1.5263x over previous
//
#include <hip/hip_runtime.h>

#define S_LEN 1024
#define HID 3584
#define NH 28
#define NKV 4
#define DH 128
#define GQ 7
#define SCALE 0.08838834764831845f
#define LOG2E 1.44269504088896f
#define CEXP (SCALE * LOG2E)
#define KDIM 3584
#define NT (KDIM / 64)

typedef float f32x4 __attribute__((ext_vector_type(4)));
typedef __bf16 bf16x8 __attribute__((ext_vector_type(8)));
typedef __bf16 bf16x4 __attribute__((ext_vector_type(4)));

#define BAR() __builtin_amdgcn_s_barrier()
#define VMCNT(n) asm volatile("s_waitcnt vmcnt(" #n ")" ::: "memory")

__device__ __forceinline__ void gl_lds16(const void* g, void* l) {
  __builtin_amdgcn_global_load_lds((const __attribute__((address_space(1))) unsigned int*)g,
                                   (__attribute__((address_space(3))) unsigned int*)l, 16, 0, 0);
}

__device__ __forceinline__ __bf16 f2bf(float f) { return (__bf16)f; }
__device__ __forceinline__ float bf2f(__bf16 h) { return (float)h; }

// ---------------- fused f32 -> bf16 convert: hs, Wq, Wk, Wv (+bias concat) ----------------
__global__ __launch_bounds__(256) void cvt_all(const float* __restrict__ hs,
                                               const float* __restrict__ Wq,
                                               const float* __restrict__ Wk,
                                               const float* __restrict__ Wv,
                                               const float* __restrict__ bq,
                                               const float* __restrict__ bk,
                                               const float* __restrict__ bv,
                                               __bf16* __restrict__ Xb,
                                               __bf16* __restrict__ Wqkv,
                                               float* __restrict__ biasq) {
  if (blockIdx.x == 11648) {
    int t = threadIdx.x;
#pragma unroll
    for (int j = 0; j < 18; ++j) {
      int i = t * 18 + j;
      biasq[i] = (i < 3584) ? bq[i] : (i < 4096 ? bk[i - 3584] : bv[i - 4096]);
    }
    return;
  }
  int i = blockIdx.x * blockDim.x + threadIdx.x;  // 8-elem units, total 2981888
  const float* src;
  __bf16* dst;
  int j;
  if (i < 917504) { src = hs; dst = Xb; j = i; }
  else if (i < 2523136) { src = Wq; dst = Wqkv; j = i - 917504; }
  else if (i < 2752512) { src = Wk; dst = Wqkv + 12845056; j = i - 2523136; }
  else { src = Wv; dst = Wqkv + 14680064; j = i - 2752512; }
  f32x4 a = ((const f32x4*)src)[2 * j], b2 = ((const f32x4*)src)[2 * j + 1];
  bf16x8 o;
  o[0] = f2bf(a[0]); o[1] = f2bf(a[1]); o[2] = f2bf(a[2]); o[3] = f2bf(a[3]);
  o[4] = f2bf(b2[0]); o[5] = f2bf(b2[1]); o[6] = f2bf(b2[2]); o[7] = f2bf(b2[3]);
  ((bf16x8*)dst)[j] = o;
}

// ============== 2-phase GEMM, 256x192 tile, QKV epilogue + Wo-cvt filler ==============
// V is written DIRECTLY in VT (B,KV,D,S) layout: acc rows i=0..3 are consecutive s
// at fixed d -> one aligned bf16x4 store (vtrans kernel eliminated).
__global__ __launch_bounds__(512, 2) void gemm192qkv(const __bf16* __restrict__ A,
                                                     const __bf16* __restrict__ Bw,
                                                     const float* __restrict__ bias,
                                                     __bf16* __restrict__ qb,
                                                     __bf16* __restrict__ kb,
                                                     __bf16* __restrict__ vt,
                                                     const float* __restrict__ Wo,
                                                     __bf16* __restrict__ Wob) {
  const int t_ = threadIdx.x;
  const int xcd = blockIdx.x & 7, slot = blockIdx.x >> 3;
  if (slot >= 24) {
    int cvtid = xcd * 8 + (slot - 24);  // 0..63
#pragma unroll
    for (int j = 0; j < 49; ++j) {
      int u = cvtid * 25088 + j * 512 + t_;
      f32x4 a = ((const f32x4*)Wo)[2 * u], b2 = ((const f32x4*)Wo)[2 * u + 1];
      bf16x8 o;
      o[0] = f2bf(a[0]); o[1] = f2bf(a[1]); o[2] = f2bf(a[2]); o[3] = f2bf(a[3]);
      o[4] = f2bf(b2[0]); o[5] = f2bf(b2[1]); o[6] = f2bf(b2[2]); o[7] = f2bf(b2[3]);
      ((bf16x8*)Wob)[u] = o;
    }
    return;
  }

  __shared__ __bf16 Asb[2][256 * 64];
  __shared__ __bf16 Bsb[2][192 * 64];
  int wg = xcd * 24 + slot;
  const long bm = (long)(wg / 24) * 256, bn = (long)(wg % 24) * 192;

  const int lane = t_ & 63, w = t_ >> 6;
  const int wm = w >> 2, wn = w & 3;
  const int l15 = lane & 15, g = lane >> 4;
  const int sw = l15 & 7;
  const int aRow0 = wm * 128 + l15, bRow0 = wn * 48 + l15;

  const int srow = t_ >> 3;
  const int cOff = ((t_ & 7) ^ (srow & 7)) << 3;
  const __bf16* Agp = A + (bm + srow) * (long)KDIM + cOff;
  const __bf16* Bgp = Bw + (bn + srow) * (long)KDIM + cOff;

  auto stageA = [&](int i, int k0, int c) {
    gl_lds16(Agp + (long)i * 64 * KDIM + k0, &Asb[c][(i * 512 + t_) * 8]);
  };
  auto stageB = [&](int i, int k0, int c) {
    gl_lds16(Bgp + (long)i * 64 * KDIM + k0, &Bsb[c][(i * 512 + t_) * 8]);
  };
  auto lda = [&](int c, int fm, int kh) -> bf16x8 {
    return *(const bf16x8*)(&Asb[c][(aRow0 + fm * 16) * 64 + (((kh * 4 + g) ^ sw) << 3)]);
  };
  auto ldb = [&](int c, int fn, int kh) -> bf16x8 {
    return *(const bf16x8*)(&Bsb[c][(bRow0 + fn * 16) * 64 + (((kh * 4 + g) ^ sw) << 3)]);
  };

  f32x4 acc[8][3] = {};
  bf16x8 a[4][2], b[3][2];

#pragma unroll
  for (int i = 0; i < 4; ++i) stageA(i, 0, 0);
#pragma unroll
  for (int i = 0; i < 3; ++i) stageB(i, 0, 0);
#pragma unroll
  for (int i = 0; i < 4; ++i) stageA(i, 64, 1);
#pragma unroll
  for (int i = 0; i < 3; ++i) stageB(i, 64, 1);
  VMCNT(7);
  BAR();

#pragma unroll 2
  for (int t = 0; t < NT; ++t) {
    const int c = t & 1;
    const int k2 = (t + 2) << 6;
    const bool n2 = (t + 2) < NT;
    // ---- P0: fm0-3 x fn0-2 ----
#pragma unroll
    for (int fm = 0; fm < 4; ++fm) { a[fm][0] = lda(c, fm, 0); a[fm][1] = lda(c, fm, 1); }
#pragma unroll
    for (int fn = 0; fn < 3; ++fn) { b[fn][0] = ldb(c, fn, 0); b[fn][1] = ldb(c, fn, 1); }
    if (t >= 1 && (t + 1) < NT) { stageA(1, (t + 1) << 6, c ^ 1); stageA(3, (t + 1) << 6, c ^ 1); }
    BAR();
    __builtin_amdgcn_s_setprio(1);
#pragma unroll
    for (int fm = 0; fm < 4; ++fm)
#pragma unroll
      for (int fn = 0; fn < 3; ++fn) {
        acc[fm][fn] = __builtin_amdgcn_mfma_f32_16x16x32_bf16(a[fm][0], b[fn][0], acc[fm][fn], 0, 0, 0);
        acc[fm][fn] = __builtin_amdgcn_mfma_f32_16x16x32_bf16(a[fm][1], b[fn][1], acc[fm][fn], 0, 0, 0);
      }
    __builtin_amdgcn_s_setprio(0);
    BAR();
    // ---- P1: fm4-7 x fn0-2 ----
#pragma unroll
    for (int fm = 0; fm < 4; ++fm) { a[fm][0] = lda(c, 4 + fm, 0); a[fm][1] = lda(c, 4 + fm, 1); }
    if (n2) { stageA(0, k2, c); stageA(2, k2, c); stageB(0, k2, c); stageB(1, k2, c); stageB(2, k2, c); }
    BAR();
    __builtin_amdgcn_s_setprio(1);
#pragma unroll
    for (int fm = 0; fm < 4; ++fm)
#pragma unroll
      for (int fn = 0; fn < 3; ++fn) {
        acc[4 + fm][fn] = __builtin_amdgcn_mfma_f32_16x16x32_bf16(a[fm][0], b[fn][0], acc[4 + fm][fn], 0, 0, 0);
        acc[4 + fm][fn] = __builtin_amdgcn_mfma_f32_16x16x32_bf16(a[fm][1], b[fn][1], acc[4 + fm][fn], 0, 0, 0);
      }
    __builtin_amdgcn_s_setprio(0);
    if (t < NT - 1) {
      if (n2) { VMCNT(5); } else { VMCNT(0); }
    }
    BAR();
  }

  // epilogue: QKV scatter (+bias); V goes directly to VT layout
#pragma unroll
  for (int fm = 0; fm < 8; ++fm) {
#pragma unroll
    for (int fn = 0; fn < 3; ++fn) {
      int col = (int)bn + wn * 48 + fn * 16 + l15;
      float bval = bias[col];
      int row0 = (int)bm + wm * 128 + fm * 16 + g * 4;
      int b_ = row0 >> 10, s0 = row0 & 1023;
      if (col < 3584) {
        int h_ = col >> 7, d_ = col & 127;
#pragma unroll
        for (int i = 0; i < 4; ++i)
          qb[((((long)b_ * NH + h_) << 10) + s0 + i) * DH + d_] = f2bf(acc[fm][fn][i] + bval);
      } else if (col < 4096) {
        int c2 = col - 3584, h_ = c2 >> 7, d_ = c2 & 127;
#pragma unroll
        for (int i = 0; i < 4; ++i)
          kb[((((long)b_ * NKV + h_) << 10) + s0 + i) * DH + d_] = f2bf(acc[fm][fn][i] + bval);
      } else {
        int c2 = col - 4096, h_ = c2 >> 7, d_ = c2 & 127;
        bf16x4 pv;
#pragma unroll
        for (int i = 0; i < 4; ++i) pv[i] = f2bf(acc[fm][fn][i] + bval);
        *(bf16x4*)(vt + ((((long)b_ * NKV + h_) * DH + d_) << 10) + s0) = pv;
      }
    }
  }
}

// ============== 2-phase GEMM, 256x128 tile, f32-out epilogue (out-proj) ==============
__global__ __launch_bounds__(512, 2) void gemm128out(const __bf16* __restrict__ A,
                                                     const __bf16* __restrict__ Bw,
                                                     float* __restrict__ outf) {
  __shared__ __bf16 Asb[2][256 * 64];
  __shared__ __bf16 Bsb[2][128 * 64];
  const int t_ = threadIdx.x;
  const int nwg = 224, NBN = 28;
  int wg = (blockIdx.x & 7) * (nwg >> 3) + (blockIdx.x >> 3);
  const long bm = (long)(wg / NBN) * 256, bn = (long)(wg % NBN) * 128;

  const int lane = t_ & 63, w = t_ >> 6;
  const int wm = w >> 2, wn = w & 3;
  const int l15 = lane & 15, g = lane >> 4;
  const int sw = l15 & 7;
  const int aRow0 = wm * 128 + l15, bRow0 = wn * 32 + l15;

  const int srow = t_ >> 3;
  const int cOff = ((t_ & 7) ^ (srow & 7)) << 3;
  const __bf16* Agp = A + (bm + srow) * (long)KDIM + cOff;
  const __bf16* Bgp = Bw + (bn + srow) * (long)KDIM + cOff;

  auto stageA = [&](int i, int k0, int c) {
    gl_lds16(Agp + (long)i * 64 * KDIM + k0, &Asb[c][(i * 512 + t_) * 8]);
  };
  auto stageB = [&](int i, int k0, int c) {
    gl_lds16(Bgp + (long)i * 64 * KDIM + k0, &Bsb[c][(i * 512 + t_) * 8]);
  };
  auto lda = [&](int c, int fm, int kh) -> bf16x8 {
    return *(const bf16x8*)(&Asb[c][(aRow0 + fm * 16) * 64 + (((kh * 4 + g) ^ sw) << 3)]);
  };
  auto ldb = [&](int c, int fn, int kh) -> bf16x8 {
    return *(const bf16x8*)(&Bsb[c][(bRow0 + fn * 16) * 64 + (((kh * 4 + g) ^ sw) << 3)]);
  };

  f32x4 acc[8][2] = {};
  bf16x8 a[4][2], b[2][2];

#pragma unroll
  for (int i = 0; i < 4; ++i) stageA(i, 0, 0);
  stageB(0, 0, 0); stageB(1, 0, 0);
#pragma unroll
  for (int i = 0; i < 4; ++i) stageA(i, 64, 1);
  stageB(0, 64, 1); stageB(1, 64, 1);
  VMCNT(6);
  BAR();

#pragma unroll 2
  for (int t = 0; t < NT; ++t) {
    const int c = t & 1;
    const int k2 = (t + 2) << 6;
    const bool n2 = (t + 2) < NT;
#pragma unroll
    for (int fm = 0; fm < 4; ++fm) { a[fm][0] = lda(c, fm, 0); a[fm][1] = lda(c, fm, 1); }
#pragma unroll
    for (int fn = 0; fn < 2; ++fn) { b[fn][0] = ldb(c, fn, 0); b[fn][1] = ldb(c, fn, 1); }
    if (t >= 1 && (t + 1) < NT) { stageA(1, (t + 1) << 6, c ^ 1); stageA(3, (t + 1) << 6, c ^ 1); }
    BAR();
    __builtin_amdgcn_s_setprio(1);
#pragma unroll
    for (int fm = 0; fm < 4; ++fm)
#pragma unroll
      for (int fn = 0; fn < 2; ++fn) {
        acc[fm][fn] = __builtin_amdgcn_mfma_f32_16x16x32_bf16(a[fm][0], b[fn][0], acc[fm][fn], 0, 0, 0);
        acc[fm][fn] = __builtin_amdgcn_mfma_f32_16x16x32_bf16(a[fm][1], b[fn][1], acc[fm][fn], 0, 0, 0);
      }
    __builtin_amdgcn_s_setprio(0);
    BAR();
#pragma unroll
    for (int fm = 0; fm < 4; ++fm) { a[fm][0] = lda(c, 4 + fm, 0); a[fm][1] = lda(c, 4 + fm, 1); }
    if (n2) { stageA(0, k2, c); stageA(2, k2, c); stageB(0, k2, c); stageB(1, k2, c); }
    BAR();
    __builtin_amdgcn_s_setprio(1);
#pragma unroll
    for (int fm = 0; fm < 4; ++fm)
#pragma unroll
      for (int fn = 0; fn < 2; ++fn) {
        acc[4 + fm][fn] = __builtin_amdgcn_mfma_f32_16x16x32_bf16(a[fm][0], b[fn][0], acc[4 + fm][fn], 0, 0, 0);
        acc[4 + fm][fn] = __builtin_amdgcn_mfma_f32_16x16x32_bf16(a[fm][1], b[fn][1], acc[4 + fm][fn], 0, 0, 0);
      }
    __builtin_amdgcn_s_setprio(0);
    if (t < NT - 1) {
      if (n2) { VMCNT(4); } else { VMCNT(0); }
    }
    BAR();
  }

#pragma unroll
  for (int fm = 0; fm < 8; ++fm) {
#pragma unroll
    for (int fn = 0; fn < 2; ++fn) {
      int col = (int)bn + wn * 32 + fn * 16 + l15;
#pragma unroll
      for (int i = 0; i < 4; ++i) {
        int row = (int)bm + wm * 128 + fm * 16 + g * 4 + i;
        outf[(long)row * HID + col] = acc[fm][fn][i];
      }
    }
  }
}

// ---------------- K-RoPE (in-place; V handled in QKV epilogue, Q in attn) ----------------
__global__ __launch_bounds__(256) void k_rope(__bf16* __restrict__ Kb,
                                              const float* __restrict__ cosb,
                                              const float* __restrict__ sinb) {
  int gid = blockIdx.x * blockDim.x + threadIdx.x;  // 524288
  int d = gid & 63;
  int r = gid >> 6;  // 0..8191
  __bf16* ptr = Kb + (long)r * DH;
  int s = r & 1023, b = r >> 12;
  const float* cb = cosb + ((long)(b << 10) + s) * DH;
  const float* sb = sinb + ((long)(b << 10) + s) * DH;
  float x1 = bf2f(ptr[d]), x2 = bf2f(ptr[d + 64]);
  ptr[d] = f2bf(x1 * cb[d] - x2 * sb[d]);
  ptr[d + 64] = f2bf(x2 * cb[d + 64] + x1 * sb[d + 64]);
}

// ---------------- fused attention (R15-verified; 2-pass, dbuf, nt P-stores, in-reg Q-RoPE) ----------------
__global__ __launch_bounds__(256) void attn_fused(const __bf16* __restrict__ Qb,
                                                  const __bf16* __restrict__ Kb,
                                                  const __bf16* __restrict__ VTb,
                                                  const float* __restrict__ cosb,
                                                  const float* __restrict__ sinb,
                                                  float* __restrict__ Pout,
                                                  __bf16* __restrict__ Ob) {
  const int bid = blockIdx.x;
  const int t = threadIdx.x;
  if (bid >= 448) {
    const int zid = bid - 448;
    f32x4 z = {0.f, 0.f, 0.f, 0.f};
    for (int cc = zid; cc < 840; cc += 64) {
      int hh = cc / 15, rt = cc % 15;
      int row = (rt << 6) + (t >> 2);
      float* rowp = Pout + ((long)hh << 20) + ((long)row << 10);
      int c0 = (rt + 1) << 6;
      int ncol4 = (1024 - c0) >> 2;
      for (int c4 = (t & 3); c4 < ncol4; c4 += 4)
        __builtin_nontemporal_store(z, (f32x4*)(rowp + c0 + c4 * 4));
    }
    return;
  }
  const int pair = bid & 7;
  const int rest = bid >> 3;  // 0..55
  const int h = rest % 28;
  const int b = rest / 28;
  const int kv = h / GQ;
  const int lane = t & 63, w = t >> 6;
  const int l15 = lane & 15, g = (lane >> 4) & 3;
  const int lk = g * 8;
  const int swz = (l15 & 7) << 3;

  __shared__ __bf16 Kt[2][64 * 128];
  __shared__ __bf16 Vt[2][128 * 64];
  __shared__ __bf16 Pl[4][16 * 68];

  const __bf16* Kg = Kb + (long)(b * NKV + kv) * S_LEN * DH;
  const __bf16* Vg = VTb + (long)(b * NKV + kv) * DH * S_LEN;
  float* Pb0 = Pout + (long)(b * NH + h) * S_LEN * S_LEN;

  auto stageK = [&](int kt, int c) {
#pragma unroll
    for (int is = 0; is < 4; ++is) {
      int chunk = is * 256 + t;
      int row = chunk >> 4, slot = chunk & 15;
      gl_lds16(Kg + (long)(kt * 64 + row) * DH + ((slot ^ (row & 7)) * 8), &Kt[c][chunk * 8]);
    }
  };
  auto stageV = [&](int kt, int c) {
#pragma unroll
    for (int is = 0; is < 4; ++is) {
      int chunk = is * 256 + t;
      int row = chunk >> 3, slot = chunk & 7;
      gl_lds16(Vg + (long)row * S_LEN + kt * 64 + ((slot ^ (row & 7)) * 8), &Vt[c][chunk * 8]);
    }
  };

  for (int halfq = 0; halfq < 2; ++halfq) {
    const int bx = halfq ? (15 - pair) : pair;
    const int q0 = bx * 64;
    const int row_q = q0 + w * 16 + l15;

    // ---- stage RAW Q (64x128, swizzled) into Kt[0]; RoPE applied in registers ----
    const __bf16* Qg = Qb + (((long)(b * NH + h) << 10) + q0) * DH;
#pragma unroll
    for (int is = 0; is < 4; ++is) {
      int chunk = is * 256 + t;
      int row = chunk >> 4, slot = chunk & 15;
      gl_lds16(Qg + (long)row * DH + ((slot ^ (row & 7)) * 8), &Kt[0][chunk * 8]);
    }
    __syncthreads();
    bf16x8 qraw[4];
#pragma unroll
    for (int kk = 0; kk < 4; ++kk)
      qraw[kk] = *(const bf16x8*)(&Kt[0][(w * 16 + l15) * 128 + ((kk * 32 + lk) ^ swz)]);
    __syncthreads();

    // in-register RoPE (fragment read cancels staging swizzle -> true column kk*32+lk+j)
    const float* cb = cosb + (((long)(b << 10) + row_q) << 7);
    const float* sb = sinb + (((long)(b << 10) + row_q) << 7);
    bf16x8 aq[4];
#pragma unroll
    for (int kk = 0; kk < 2; ++kk) {
      int dbase = kk * 32 + lk;  // true column in [0,64), 8-aligned
      f32x4 c0 = *(const f32x4*)(cb + dbase), c1 = *(const f32x4*)(cb + dbase + 4);
      f32x4 s0 = *(const f32x4*)(sb + dbase), s1 = *(const f32x4*)(sb + dbase + 4);
      f32x4 c2 = *(const f32x4*)(cb + dbase + 64), c3 = *(const f32x4*)(cb + dbase + 68);
      f32x4 s2 = *(const f32x4*)(sb + dbase + 64), s3 = *(const f32x4*)(sb + dbase + 68);
#pragma unroll
      for (int j = 0; j < 4; ++j) {
        float lo0 = bf2f(qraw[kk][j]), hi0 = bf2f(qraw[kk + 2][j]);
        float lo1 = bf2f(qraw[kk][4 + j]), hi1 = bf2f(qraw[kk + 2][4 + j]);
        aq[kk][j] = f2bf(lo0 * c0[j] - hi0 * s0[j]);
        aq[kk][4 + j] = f2bf(lo1 * c1[j] - hi1 * s1[j]);
        aq[kk + 2][j] = f2bf(hi0 * c2[j] + lo0 * s2[j]);
        aq[kk + 2][4 + j] = f2bf(hi1 * c3[j] + lo1 * s3[j]);
      }
    }

    // ---------- pass 1: row sums (fixed max = 0), K double-buffered ----------
    stageK(0, 0);
    float lsum = 0.f;
    for (int kt = 0; kt <= bx; ++kt) {
      const int c = kt & 1;
      if (kt < bx) { stageK(kt + 1, c ^ 1); VMCNT(4); } else { VMCNT(0); }
      BAR();
#pragma unroll
      for (int fn = 0; fn < 4; ++fn) {
        f32x4 acc = {};
#pragma unroll
        for (int kk = 0; kk < 4; ++kk) {
          bf16x8 kf = *(const bf16x8*)(&Kt[c][(fn * 16 + l15) * 128 + ((kk * 32 + lk) ^ swz)]);
          acc = __builtin_amdgcn_mfma_f32_16x16x32_bf16(kf, aq[kk], acc, 0, 0, 0);
        }
        int colbase = kt * 64 + fn * 16 + g * 4;
#pragma unroll
        for (int i = 0; i < 4; ++i)
          lsum += (colbase + i <= row_q) ? exp2f(acc[i] * CEXP) : 0.f;
      }
      BAR();
    }
    lsum += __shfl_xor(lsum, 16);
    lsum += __shfl_xor(lsum, 32);
    const float il = 1.f / lsum;

    // ---------- pass 2: write P (nontemporal), accumulate O ----------
    f32x4 oa[8] = {};
    stageK(0, 0);
    stageV(0, 0);
    for (int kt = 0; kt <= bx; ++kt) {
      const int c = kt & 1;
      if (kt < bx) {
        stageK(kt + 1, c ^ 1);
        stageV(kt + 1, c ^ 1);
        if (kt == 0) { VMCNT(8); } else { VMCNT(12); }
      } else {
        VMCNT(0);
      }
      BAR();
#pragma unroll
      for (int fn = 0; fn < 4; ++fn) {
        f32x4 acc = {};
#pragma unroll
        for (int kk = 0; kk < 4; ++kk) {
          bf16x8 kf = *(const bf16x8*)(&Kt[c][(fn * 16 + l15) * 128 + ((kk * 32 + lk) ^ swz)]);
          acc = __builtin_amdgcn_mfma_f32_16x16x32_bf16(kf, aq[kk], acc, 0, 0, 0);
        }
        int colbase = kt * 64 + fn * 16 + g * 4;
        f32x4 pv;
        bf16x4 pb;
#pragma unroll
        for (int i = 0; i < 4; ++i) {
          float e = (colbase + i <= row_q) ? exp2f(acc[i] * CEXP) * il : 0.f;
          pv[i] = e;
          pb[i] = f2bf(e);
        }
        __builtin_nontemporal_store(pv, (f32x4*)(Pb0 + ((long)row_q << 10) + colbase));
        *(bf16x4*)(&Pl[w][l15 * 68 + fn * 16 + g * 4]) = pb;
      }
      bf16x8 ap0 = *(const bf16x8*)(&Pl[w][l15 * 68 + lk]);
      bf16x8 ap1 = *(const bf16x8*)(&Pl[w][l15 * 68 + 32 + lk]);
#pragma unroll
      for (int dn = 0; dn < 8; ++dn) {
        bf16x8 bv0 = *(const bf16x8*)(&Vt[c][(dn * 16 + l15) * 64 + (lk ^ swz)]);
        bf16x8 bv1 = *(const bf16x8*)(&Vt[c][(dn * 16 + l15) * 64 + ((32 + lk) ^ swz)]);
        oa[dn] = __builtin_amdgcn_mfma_f32_16x16x32_bf16(ap0, bv0, oa[dn], 0, 0, 0);
        oa[dn] = __builtin_amdgcn_mfma_f32_16x16x32_bf16(ap1, bv1, oa[dn], 0, 0, 0);
      }
      BAR();
    }

    // write O (bf16, (B,S,H*D))
#pragma unroll
    for (int dn = 0; dn < 8; ++dn) {
#pragma unroll
      for (int i = 0; i < 4; ++i) {
        int row = q0 + w * 16 + g * 4 + i;
        Ob[(long)(b * S_LEN + row) * HID + h * DH + dn * 16 + l15] = f2bf(oa[dn][i]);
      }
    }
  }
}

extern "C" void kernel_launch(void* const* d_in, const int* in_sizes, int n_in,
                              void* d_out, int out_size, void* d_ws, size_t ws_size,
                              hipStream_t stream) {
  const float* hs = (const float*)d_in[0];
  const float* cosb = (const float*)d_in[1];
  const float* sinb = (const float*)d_in[2];
  const float* Wq = (const float*)d_in[4];
  const float* bq = (const float*)d_in[5];
  const float* Wk = (const float*)d_in[6];
  const float* bk = (const float*)d_in[7];
  const float* Wv = (const float*)d_in[8];
  const float* bv = (const float*)d_in[9];
  const float* Wo = (const float*)d_in[10];

  float* out = (float*)d_out;
  float* attn_out = out;             // 2*1024*3584
  float* attn_w = out + 7340032;     // 2*28*1024*1024

  char* ws = (char*)d_ws;
  size_t off = 0;
  auto alloc = [&](size_t bytes) {
    void* p = ws + off;
    off += (bytes + 255) & ~(size_t)255;
    return p;
  };
  __bf16* Xb = (__bf16*)alloc(2048LL * 3584 * 2);
  __bf16* Wqkv = (__bf16*)alloc(4608LL * 3584 * 2);
  __bf16* Wob = (__bf16*)alloc(3584LL * 3584 * 2);
  float* biasq = (float*)alloc(4608 * 4);
  __bf16* Qb = (__bf16*)alloc(2LL * 28 * 1024 * 128 * 2);
  __bf16* Kb = (__bf16*)alloc(2LL * 4 * 1024 * 128 * 2);
  __bf16* VT = (__bf16*)alloc(2LL * 4 * 1024 * 128 * 2);
  __bf16* Ob = (__bf16*)alloc(2048LL * 3584 * 2);

  // converts hs, Wq, Wk, Wv (+bias); Wo handled by gemm192qkv's filler blocks
  cvt_all<<<11649, 256, 0, stream>>>(hs, Wq, Wk, Wv, bq, bk, bv, Xb, Wqkv, biasq);

  // slot<24 (24/XCD): QKV GEMM (192 blocks); slot>=24: Wo cvt (64 blocks).
  // V is written directly in VT layout by the epilogue.
  gemm192qkv<<<256, 512, 0, stream>>>(Xb, Wqkv, biasq, Qb, Kb, VT, Wo, Wob);

  // K-RoPE only (Q-RoPE in attn, V-transpose in QKV epilogue)
  k_rope<<<2048, 256, 0, stream>>>(Kb, cosb, sinb);

  // 448 compute blocks + 64 zero-fill filler blocks (all co-resident at 2/CU)
  attn_fused<<<512, 256, 0, stream>>>(Qb, Kb, VT, cosb, sinb, attn_w, Ob);

  gemm128out<<<224, 512, 0, stream>>>(Ob, Wob, attn_out);
}